// Round 12
// baseline (534.644 us; speedup 1.0000x reference)
//
#include <hip/hip_runtime.h>
#include <hip/hip_fp16.h>
#include <math.h>

// ---------------------------------------------------------------------------
// PNA (2 conv layers) on MI355X.
//   pre:  [A|B] = x @ [Wl|Wr]^T (+b on B)   (bf16-split MFMA GEMM; B -> fp16)
//   CSR build: hist -> scan -> 2-level bucket sort (no write amplification)
//   gathers: 4 features/lane x 4 edges/wave-step packed fp16 gather
//            (uint2 loads, v_pk_min/max_f16 via asm, f32 sum/sq, shfl combine)
//   post1: bf16-split MFMA GEMM, fragment-major weights, LDS double-buffered
//          weight staging via global_load_lds (async, no VGPR round-trip)
//   fused_conv2: packed gather + 2-col dot (no aggr materialization)
// ---------------------------------------------------------------------------

typedef __attribute__((ext_vector_type(4))) float f32x4;
typedef __attribute__((ext_vector_type(8))) short s16x8;

#define AS1 __attribute__((address_space(1)))
#define AS3 __attribute__((address_space(3)))
__device__ inline void gload16(const void* g, void* l) {
  __builtin_amdgcn_global_load_lds((AS1 const void*)g, (AS3 void*)l, 16, 0, 0);
}

__device__ inline unsigned pkmax16(unsigned a, unsigned b) {
  unsigned r;
  asm("v_pk_max_f16 %0, %1, %2" : "=v"(r) : "v"(a), "v"(b));
  return r;
}
__device__ inline unsigned pkmin16(unsigned a, unsigned b) {
  unsigned r;
  asm("v_pk_min_f16 %0, %1, %2" : "=v"(r) : "v"(a), "v"(b));
  return r;
}

__device__ inline unsigned short f2bf(float f) {
  unsigned int u = __float_as_uint(f);
  unsigned int r = u + 0x7fff + ((u >> 16) & 1);  // RNE
  return (unsigned short)(r >> 16);
}
__device__ inline float bf2f(unsigned short s) {
  return __uint_as_float(((unsigned int)s) << 16);
}
// truncation split: v = hi + rest, lo = bf16(rest)
__device__ inline void tsplit(float v, unsigned short& h, unsigned short& l) {
  unsigned int u = __float_as_uint(v);
  unsigned int hu = u & 0xffff0000u;
  h = (unsigned short)(hu >> 16);
  float lf = v - __uint_as_float(hu);
  l = (unsigned short)(__float_as_uint(lf) >> 16);
}

#define ME_S0 (64 * 832)
#define ME_S1 (ME_S0 + 64)
#define ME_S2 (ME_S1 + 2 * 832)
#define ME_S3 (ME_S2 + 2)
#define ME_S4 (ME_S3 + 128 * 64)
#define ME_S5 (ME_S4 + 128 * 64)

__global__ void make_eff_kernel(const float* __restrict__ W1_post, const float* __restrict__ b1_post,
                                const float* __restrict__ W1_lin, const float* __restrict__ b1_lin,
                                const float* __restrict__ W2_post, const float* __restrict__ b2_post,
                                const float* __restrict__ W2_lin, const float* __restrict__ b2_lin,
                                const float* __restrict__ W1_pre, const float* __restrict__ W2_pre,
                                unsigned short* __restrict__ W1h, unsigned short* __restrict__ W1l,
                                float* __restrict__ b1eff,
                                float* __restrict__ W2eff, float* __restrict__ b2eff,
                                unsigned short* __restrict__ Wp1h, unsigned short* __restrict__ Wp1l,
                                unsigned short* __restrict__ Wp2h, unsigned short* __restrict__ Wp2l) {
  int id = blockIdx.x * blockDim.x + threadIdx.x;
  if (id < ME_S0) {
    int o = id / 832, k = id - o * 832;
    float s = 0.f;
#pragma unroll 8
    for (int j = 0; j < 64; ++j) s = fmaf(W1_lin[o * 64 + j], W1_post[j * 832 + k], s);
    unsigned short h = f2bf(s);
    unsigned short l = f2bf(s - bf2f(h));
    // fragment-major layout: lane = klg*16 + ar holds elems j for (col, k)
    int q = k >> 5, klg = (k >> 3) & 3, jj = k & 7;
    int ct = o >> 4, ar = o & 15;
    int idx = ((q * 4 + ct) * 64 + (klg * 16 + ar)) * 8 + jj;
    W1h[idx] = h;
    W1l[idx] = l;
  } else if (id < ME_S1) {
    int o = id - ME_S0;
    float s = b1_lin[o];
    for (int j = 0; j < 64; ++j) s = fmaf(W1_lin[o * 64 + j], b1_post[j], s);
    b1eff[o] = s;
  } else if (id < ME_S2) {
    int t = id - ME_S1;
    int o = t / 832, k = t - o * 832;
    W2eff[t] = fmaf(W2_lin[o * 2 + 0], W2_post[k], W2_lin[o * 2 + 1] * W2_post[832 + k]);
  } else if (id < ME_S3) {
    int o = id - ME_S2;
    b2eff[o] = b2_lin[o] + W2_lin[o * 2 + 0] * b2_post[0] + W2_lin[o * 2 + 1] * b2_post[1];
  } else if (id < ME_S4) {
    int t = id - ME_S3;
    int c = t >> 6, k = t & 63;
    float v = (c < 64) ? W1_pre[c * 128 + k] : W1_pre[(c - 64) * 128 + 64 + k];
    unsigned short h = f2bf(v);
    Wp1h[t] = h;
    Wp1l[t] = f2bf(v - bf2f(h));
  } else if (id < ME_S5) {
    int t = id - ME_S4;
    int c = t >> 6, k = t & 63;
    float v = (c < 64) ? W2_pre[c * 128 + k] : W2_pre[(c - 64) * 128 + 64 + k];
    unsigned short h = f2bf(v);
    Wp2h[t] = h;
    Wp2l[t] = f2bf(v - bf2f(h));
  }
}

__global__ void hist_kernel(const int* __restrict__ dst, int* __restrict__ deg, int E) {
  int i = blockIdx.x * blockDim.x + threadIdx.x;
  if (i < E) atomicAdd(&deg[dst[i]], 1);
}

__global__ void avglog_kernel(const int* __restrict__ deg, float* __restrict__ out_sum, int n) {
  int i = blockIdx.x * blockDim.x + threadIdx.x;
  float v = (i < n) ? logf((float)deg[i] + 1.0f) : 0.0f;
  __shared__ float red[4];
  int lane = threadIdx.x & 63, wid = threadIdx.x >> 6;
  for (int off = 32; off; off >>= 1) v += __shfl_down(v, off);
  if (lane == 0) red[wid] = v;
  __syncthreads();
  if (threadIdx.x == 0) atomicAdd(out_sum, red[0] + red[1] + red[2] + red[3]);
}

__global__ void scan1_kernel(const int* __restrict__ deg, int* __restrict__ excl,
                             int* __restrict__ partial, int n) {
  __shared__ int wsums[4];
  int tid = threadIdx.x, b = blockIdx.x;
  int i = b * 256 + tid;
  int lane = tid & 63, wid = tid >> 6;
  int v = (i < n) ? deg[i] : 0;
  int x = v;
  for (int off = 1; off < 64; off <<= 1) {
    int t = __shfl_up(x, off);
    if (lane >= off) x += t;
  }
  if (lane == 63) wsums[wid] = x;
  __syncthreads();
  int wo = 0;
#pragma unroll
  for (int j = 0; j < 4; ++j) wo += (j < wid) ? wsums[j] : 0;
  if (i < n) excl[i] = wo + x - v;
  if (tid == 255) partial[b] = wo + x;
}

__global__ void scan2_kernel(int* __restrict__ partial, int nb) {
  __shared__ int wsums[16];
  int tid = threadIdx.x;
  int lane = tid & 63, wid = tid >> 6;
  int v = (tid < nb) ? partial[tid] : 0;
  int x = v;
  for (int off = 1; off < 64; off <<= 1) {
    int t = __shfl_up(x, off);
    if (lane >= off) x += t;
  }
  if (lane == 63) wsums[wid] = x;
  __syncthreads();
  if (wid == 0) {
    int w2 = (lane < 16) ? wsums[lane] : 0;
    for (int off = 1; off < 16; off <<= 1) {
      int t = __shfl_up(w2, off);
      if (lane >= off) w2 += t;
    }
    if (lane < 16) wsums[lane] = w2;
  }
  __syncthreads();
  int wo = (wid > 0) ? wsums[wid - 1] : 0;
  if (tid < nb) partial[tid] = wo + x - v;
}

__global__ void scan3_kernel(const int* __restrict__ deg, const int* __restrict__ excl,
                             const int* __restrict__ partial, int* __restrict__ rowptr,
                             int* __restrict__ cursor, float* __restrict__ amp,
                             float* __restrict__ inv, const float* __restrict__ avgsum,
                             int n, int E) {
  int i = blockIdx.x * 256 + threadIdx.x;
  if (i < n) {
    int r = excl[i] + partial[blockIdx.x];
    rowptr[i] = r;
    cursor[i] = r;
    int v = deg[i];
    float dnm = (float)(v > 0 ? v : 1);
    float a = logf(dnm + 1.0f) * ((float)n / avgsum[0]);
    amp[i] = a;
    inv[i] = 1.0f / a;
  }
  if (i == 0) rowptr[n] = E;
}

// ---- 2-level bucket sort CSR build (bucket = 1024 dst nodes) ----
#define BMAX 104
#define BINCAP 72
#define ACHUNK 4096

__global__ void bucket_init(const int* __restrict__ rowptr, int* __restrict__ bcur,
                            int n, int nbuk) {
  int b = blockIdx.x * blockDim.x + threadIdx.x;
  if (b < nbuk) {
    int idx = b << 10;
    if (idx > n) idx = n;
    bcur[b] = rowptr[idx];
  }
}

__global__ __launch_bounds__(256) void bucket_scatter(
    const int* __restrict__ src, const int* __restrict__ dst,
    int* __restrict__ bcur, int2* __restrict__ bmaj, int E, int nbuk) {
  __shared__ int bin_cnt[BMAX];
  __shared__ int bin_len[BMAX];
  __shared__ int bin_base[BMAX];
  __shared__ int bin_pref[BMAX + 1];
  __shared__ int2 bin_buf[BMAX * BINCAP];
  int tid = threadIdx.x;
  for (int b = tid; b < BMAX; b += 256) bin_cnt[b] = 0;
  __syncthreads();
  int start = blockIdx.x * ACHUNK;
  int end = start + ACHUNK;
  if (end > E) end = E;
  for (int i = start + tid; i < end; i += 256) {
    int s = src[i], d = dst[i];
    int b = d >> 10;
    int slot = atomicAdd(&bin_cnt[b], 1);
    if (slot < BINCAP) {
      bin_buf[b * BINCAP + slot] = make_int2(s, d);
    } else {
      int pos = atomicAdd(&bcur[b], 1);
      bmaj[pos] = make_int2(s, d);
    }
  }
  __syncthreads();
  if (tid < nbuk) {
    int c = bin_cnt[tid];
    bin_len[tid] = (c < BINCAP) ? c : BINCAP;
  }
  __syncthreads();
  if (tid == 0) {
    int acc = 0;
    for (int b = 0; b < nbuk; ++b) {
      bin_pref[b] = acc;
      acc += bin_len[b];
    }
    bin_pref[nbuk] = acc;
  }
  __syncthreads();
  if (tid < nbuk && bin_len[tid] > 0) bin_base[tid] = atomicAdd(&bcur[tid], bin_len[tid]);
  __syncthreads();
  int T = bin_pref[nbuk];
  for (int t = tid; t < T; t += 256) {
    int lo = 0, hi = nbuk - 1;
    while (lo < hi) {
      int mid = (lo + hi + 1) >> 1;
      if (bin_pref[mid] <= t) lo = mid; else hi = mid - 1;
    }
    int j = t - bin_pref[lo];
    bmaj[bin_base[lo] + j] = bin_buf[lo * BINCAP + j];
  }
}

__global__ __launch_bounds__(1024) void bucket_fill(
    const int2* __restrict__ bmaj, const int* __restrict__ rowptr,
    int* __restrict__ cursor, int* __restrict__ col, int n, int E) {
  int b = blockIdx.x;
  int i0 = b << 10;
  int i1 = i0 + 1024;
  if (i0 > n) i0 = n;
  if (i1 > n) i1 = n;
  int start = rowptr[i0];
  int end = rowptr[i1];
  for (int e = start + (int)threadIdx.x; e < end; e += 1024) {
    int2 p = bmaj[e];
    int pos = atomicAdd(&cursor[p.y], 1);
    col[pos] = p.x;
  }
}

// [A|B] = x @ [Wl|Wr]^T, bias folded into B (B stored fp16). 128-row blocks.
__global__ __launch_bounds__(256, 2) void pre_mfma(
    const float* __restrict__ xin, const unsigned short* __restrict__ Wh,
    const unsigned short* __restrict__ Wl, const float* __restrict__ bias,
    float* __restrict__ A, __half* __restrict__ Bo, int n) {
  __shared__ __attribute__((aligned(16))) unsigned short XH[128 * 64];
  __shared__ __attribute__((aligned(16))) unsigned short XL[128 * 64];
  int tid = threadIdx.x;
  int lane = tid & 63, w = tid >> 6;
  int row0 = blockIdx.x * 128;
  int sr = tid >> 1, hf = tid & 1;
  int grow = row0 + sr;
  {
    float v[32];
    if (grow < n) {
      const float4* p = (const float4*)(xin + (size_t)grow * 64 + hf * 32);
#pragma unroll
      for (int q = 0; q < 8; ++q) {
        float4 t = p[q];
        v[q * 4 + 0] = t.x; v[q * 4 + 1] = t.y; v[q * 4 + 2] = t.z; v[q * 4 + 3] = t.w;
      }
    } else {
#pragma unroll
      for (int j = 0; j < 32; ++j) v[j] = 0.f;
    }
    unsigned short hs[32], ls[32];
#pragma unroll
    for (int j = 0; j < 32; ++j) tsplit(v[j], hs[j], ls[j]);
    int rsw = sr & 7;
#pragma unroll
    for (int q = 0; q < 4; ++q) {
      int g = hf * 4 + q;
      int off = sr * 64 + ((g ^ rsw) << 3);
      *(s16x8*)&XH[off] = *(const s16x8*)&hs[q * 8];
      *(s16x8*)&XL[off] = *(const s16x8*)&ls[q * 8];
    }
  }
  __syncthreads();
  int ar = lane & 15, klg = lane >> 4;
  f32x4 acc[2][8];
#pragma unroll
  for (int rf = 0; rf < 2; ++rf)
#pragma unroll
    for (int ct = 0; ct < 8; ++ct) acc[rf][ct] = (f32x4){0.f, 0.f, 0.f, 0.f};
#pragma unroll
  for (int kk = 0; kk < 64; kk += 32) {
    s16x8 ah[2], al[2];
#pragma unroll
    for (int rf = 0; rf < 2; ++rf) {
      int lrow = w * 32 + rf * 16 + ar;
      int g = (kk >> 3) + klg;
      int off = lrow * 64 + ((g ^ (lrow & 7)) << 3);
      ah[rf] = *(const s16x8*)&XH[off];
      al[rf] = *(const s16x8*)&XL[off];
    }
    int ko = kk + klg * 8;
#pragma unroll
    for (int ct = 0; ct < 8; ++ct) {
      size_t br = (size_t)(ct * 16 + ar) * 64 + ko;
      s16x8 bh = *(const s16x8*)&Wh[br];
      s16x8 bl = *(const s16x8*)&Wl[br];
#pragma unroll
      for (int rf = 0; rf < 2; ++rf) {
        acc[rf][ct] = __builtin_amdgcn_mfma_f32_16x16x32_bf16(ah[rf], bh, acc[rf][ct], 0, 0, 0);
        acc[rf][ct] = __builtin_amdgcn_mfma_f32_16x16x32_bf16(ah[rf], bl, acc[rf][ct], 0, 0, 0);
        acc[rf][ct] = __builtin_amdgcn_mfma_f32_16x16x32_bf16(al[rf], bh, acc[rf][ct], 0, 0, 0);
      }
    }
  }
#pragma unroll
  for (int rf = 0; rf < 2; ++rf)
#pragma unroll
    for (int i = 0; i < 4; ++i) {
      int r = row0 + w * 32 + rf * 16 + klg * 4 + i;
      if (r < n) {
#pragma unroll
        for (int ct = 0; ct < 8; ++ct) {
          int c = ct * 16 + ar;
          float vv = acc[rf][ct][i];
          if (ct < 4) A[(size_t)r * 64 + c] = vv;
          else Bo[(size_t)r * 64 + (c - 64)] = __float2half(vv + bias[c - 64]);
        }
      }
    }
}

// ---- packed gather: lane = (eg=lane>>4 edge-group, fl=lane&15 feat-group) ----
// Each lane loads 4 fp16 feats (uint2) of its group's edge; 4 edges/wave-step.
__device__ __forceinline__ void gather_stats4(
    const __half* __restrict__ B, const int* __restrict__ col,
    int s0, int s1, int fl, int eg,
    float4& sum4, float4& sq4, float4& mn4, float4& mx4) {
  float2 s01 = make_float2(0.f, 0.f), s23 = s01, q01 = s01, q23 = s01;
  unsigned mx01 = 0xFC00FC00u, mx23 = 0xFC00FC00u;  // -inf pairs
  unsigned mn01 = 0x7C007C00u, mn23 = 0x7C007C00u;  // +inf pairs
  auto proc = [&](uint2 v) {
    float2 f01 = __half22float2(*(__half2*)&v.x);
    float2 f23 = __half22float2(*(__half2*)&v.y);
    s01.x += f01.x; s01.y += f01.y;
    s23.x += f23.x; s23.y += f23.y;
    q01.x = fmaf(f01.x, f01.x, q01.x); q01.y = fmaf(f01.y, f01.y, q01.y);
    q23.x = fmaf(f23.x, f23.x, q23.x); q23.y = fmaf(f23.y, f23.y, q23.y);
    mx01 = pkmax16(mx01, v.x); mx23 = pkmax16(mx23, v.y);
    mn01 = pkmin16(mn01, v.x); mn23 = pkmin16(mn23, v.y);
  };
  int e = s0;
  for (; e + 16 <= s1; e += 16) {
    int base = e + eg * 4;
    int c0 = col[base], c1 = col[base + 1], c2 = col[base + 2], c3 = col[base + 3];
    uint2 v0 = *(const uint2*)&B[(size_t)c0 * 64 + fl * 4];
    uint2 v1 = *(const uint2*)&B[(size_t)c1 * 64 + fl * 4];
    uint2 v2 = *(const uint2*)&B[(size_t)c2 * 64 + fl * 4];
    uint2 v3 = *(const uint2*)&B[(size_t)c3 * 64 + fl * 4];
    proc(v0); proc(v1); proc(v2); proc(v3);
  }
  if (e < s1) {  // masked tail (< 16 edges)
    int base = e + eg * 4;
#pragma unroll
    for (int q = 0; q < 4; ++q) {
      int gpos = base + q;
      bool valid = gpos < s1;
      int gc = valid ? gpos : (s1 - 1);
      int ci = col[gc];
      uint2 v = *(const uint2*)&B[(size_t)ci * 64 + fl * 4];
      if (valid) proc(v);
    }
  }
  // combine the 4 edge groups (xor 16, 32)
#pragma unroll
  for (int m = 16; m <= 32; m <<= 1) {
    s01.x += __shfl_xor(s01.x, m); s01.y += __shfl_xor(s01.y, m);
    s23.x += __shfl_xor(s23.x, m); s23.y += __shfl_xor(s23.y, m);
    q01.x += __shfl_xor(q01.x, m); q01.y += __shfl_xor(q01.y, m);
    q23.x += __shfl_xor(q23.x, m); q23.y += __shfl_xor(q23.y, m);
    unsigned u;
    u = (unsigned)__shfl_xor((int)mx01, m); mx01 = pkmax16(mx01, u);
    u = (unsigned)__shfl_xor((int)mx23, m); mx23 = pkmax16(mx23, u);
    u = (unsigned)__shfl_xor((int)mn01, m); mn01 = pkmin16(mn01, u);
    u = (unsigned)__shfl_xor((int)mn23, m); mn23 = pkmin16(mn23, u);
  }
  sum4 = make_float4(s01.x, s01.y, s23.x, s23.y);
  sq4 = make_float4(q01.x, q01.y, q23.x, q23.y);
  float2 t0 = __half22float2(*(__half2*)&mn01);
  float2 t1 = __half22float2(*(__half2*)&mn23);
  mn4 = make_float4(t0.x, t0.y, t1.x, t1.y);
  t0 = __half22float2(*(__half2*)&mx01);
  t1 = __half22float2(*(__half2*)&mx23);
  mx4 = make_float4(t0.x, t0.y, t1.x, t1.y);
}

// finalize stats for 4 features: st0=mean, st1=min, st2=max, st3=std
__device__ __forceinline__ void finalize4(const float* __restrict__ A, int node,
                                          int fl, int d,
                                          const float4& sum4, const float4& sq4,
                                          const float4& mn4, const float4& mx4,
                                          float4& st0, float4& st1, float4& st2, float4& st3) {
  if (d > 0) {
    float idn = 1.0f / (float)d;
    float4 a4 = *(const float4*)&A[(size_t)node * 64 + fl * 4];
    float4 mB = make_float4(sum4.x * idn, sum4.y * idn, sum4.z * idn, sum4.w * idn);
    st0 = make_float4(a4.x + mB.x, a4.y + mB.y, a4.z + mB.z, a4.w + mB.w);
    st1 = make_float4(a4.x + mn4.x, a4.y + mn4.y, a4.z + mn4.z, a4.w + mn4.w);
    st2 = make_float4(a4.x + mx4.x, a4.y + mx4.y, a4.z + mx4.z, a4.w + mx4.w);
    st3 = make_float4(
        sqrtf(fmaxf(fmaf(-mB.x, mB.x, sq4.x * idn), 0.f) + 1e-5f),
        sqrtf(fmaxf(fmaf(-mB.y, mB.y, sq4.y * idn), 0.f) + 1e-5f),
        sqrtf(fmaxf(fmaf(-mB.z, mB.z, sq4.z * idn), 0.f) + 1e-5f),
        sqrtf(fmaxf(fmaf(-mB.w, mB.w, sq4.w * idn), 0.f) + 1e-5f));
  } else {
    st0 = make_float4(0.f, 0.f, 0.f, 0.f);
    st1 = st0; st2 = st0;
    float s = sqrtf(1e-5f);
    st3 = make_float4(s, s, s, s);
  }
}

__device__ __forceinline__ void pack_write(unsigned short* __restrict__ H,
                                           unsigned short* __restrict__ L,
                                           size_t o, float4 v) {
  unsigned short h0, h1, h2, h3, l0, l1, l2, l3;
  tsplit(v.x, h0, l0); tsplit(v.y, h1, l1);
  tsplit(v.z, h2, l2); tsplit(v.w, h3, l3);
  uint2 hp, lp;
  hp.x = (unsigned)h0 | ((unsigned)h1 << 16);
  hp.y = (unsigned)h2 | ((unsigned)h3 << 16);
  lp.x = (unsigned)l0 | ((unsigned)l1 << 16);
  lp.y = (unsigned)l2 | ((unsigned)l3 << 16);
  *(uint2*)&H[o] = hp;
  *(uint2*)&L[o] = lp;
}

// wave per node: packed gather stats -> bf16 hi/lo Agg
__global__ __launch_bounds__(256) void aggr_pack(
    const float* __restrict__ A, const __half* __restrict__ B,
    const int* __restrict__ rowptr, const int* __restrict__ col,
    unsigned short* __restrict__ AggH, unsigned short* __restrict__ AggL, int n) {
  int tid = threadIdx.x;
  int lane = tid & 63, wv = tid >> 6;
  int fl = lane & 15, eg = lane >> 4;
  int node = blockIdx.x * 4 + wv;
  if (node >= n) return;
  int s0 = rowptr[node], s1 = rowptr[node + 1];
  float4 sum4, sq4, mn4, mx4;
  gather_stats4(B, col, s0, s1, fl, eg, sum4, sq4, mn4, mx4);
  float4 st0, st1, st2, st3;
  finalize4(A, node, fl, s1 - s0, sum4, sq4, mn4, mx4, st0, st1, st2, st3);
  if (eg == 0) {
    size_t o = (size_t)node * 256 + fl * 4;
    pack_write(AggH, AggL, o, st0);
    pack_write(AggH, AggL, o + 64, st1);
    pack_write(AggH, AggL, o + 128, st2);
    pack_write(AggH, AggL, o + 192, st3);
  }
}

// post1: bf16-split MFMA GEMM, 128-row blocks, 4 waves x 32 rows.
// Weights fragment-major, streamed through LDS in 13 double-buffered 16KB
// chunks via global_load_lds (async direct-to-LDS; issued before compute).
__global__ __launch_bounds__(256) void post1_kernel(
    const float* __restrict__ x,
    const unsigned short* __restrict__ AggH, const unsigned short* __restrict__ AggL,
    const float* __restrict__ amp, const float* __restrict__ inv,
    const unsigned short* __restrict__ Wh, const unsigned short* __restrict__ Wl,
    const float* __restrict__ beff, float* __restrict__ h1, int n) {
  __shared__ __attribute__((aligned(16))) unsigned short WS[16384];  // 2 x (4K Wh + 4K Wl)
  int tid = threadIdx.x;
  int lane = tid & 63, w = tid >> 6;
  int row0 = blockIdx.x * 128;
  int ar = lane & 15, klg = lane >> 4;
  int grow[2];
  bool rok[2];
#pragma unroll
  for (int rf = 0; rf < 2; ++rf) {
    grow[rf] = row0 + w * 32 + rf * 16 + ar;
    rok[rf] = grow[rf] < n;
  }
  f32x4 accP[2][4], accQ[2][4], accR[2][4];
#pragma unroll
  for (int rf = 0; rf < 2; ++rf)
#pragma unroll
    for (int ct = 0; ct < 4; ++ct) {
      accP[rf][ct] = (f32x4){0.f, 0.f, 0.f, 0.f};
      accQ[rf][ct] = (f32x4){0.f, 0.f, 0.f, 0.f};
      accR[rf][ct] = (f32x4){0.f, 0.f, 0.f, 0.f};
    }

  int w2 = w & 1;
  auto stage = [&](int c, int buf) {
    const unsigned short* srcbase = (w < 2) ? (Wh + c * 4096) : (Wl + c * 4096);
    unsigned short* dstbase = &WS[buf * 8192 + (w < 2 ? 0 : 4096)];
#pragma unroll
    for (int i = 0; i < 4; ++i) {
      int boff = w2 * 2048 + i * 512 + lane * 8;  // elements (2B each)
      gload16(srcbase + boff, dstbase + boff);
    }
  };

  stage(0, 0);
  __syncthreads();

#pragma unroll
  for (int cidx = 0; cidx < 13; ++cidx) {
    int cur = cidx & 1;
    if (cidx + 1 < 13) stage(cidx + 1, cur ^ 1);
    const unsigned short* WHc = &WS[cur * 8192];
    const unsigned short* WLc = &WS[cur * 8192 + 4096];
    if (cidx == 0) {
#pragma unroll
      for (int l = 0; l < 2; ++l) {
        s16x8 ah[2], al[2];
#pragma unroll
        for (int rf = 0; rf < 2; ++rf) {
          unsigned short hs[8], ls[8];
          if (rok[rf]) {
            const float* p = x + (size_t)grow[rf] * 64 + l * 32 + klg * 8;
            float4 v0 = *(const float4*)p;
            float4 v1 = *(const float4*)(p + 4);
            float vv[8] = {v0.x, v0.y, v0.z, v0.w, v1.x, v1.y, v1.z, v1.w};
#pragma unroll
            for (int j = 0; j < 8; ++j) tsplit(vv[j], hs[j], ls[j]);
          } else {
#pragma unroll
            for (int j = 0; j < 8; ++j) { hs[j] = 0; ls[j] = 0; }
          }
          ah[rf] = *(const s16x8*)hs;
          al[rf] = *(const s16x8*)ls;
        }
#pragma unroll
        for (int ct = 0; ct < 4; ++ct) {
          int fo = ((l * 4 + ct) * 64 + lane) * 8;
          s16x8 bh = *(const s16x8*)&WHc[fo];
          s16x8 bl = *(const s16x8*)&WLc[fo];
#pragma unroll
          for (int rf = 0; rf < 2; ++rf) {
            accP[rf][ct] = __builtin_amdgcn_mfma_f32_16x16x32_bf16(ah[rf], bh, accP[rf][ct], 0, 0, 0);
            accP[rf][ct] = __builtin_amdgcn_mfma_f32_16x16x32_bf16(ah[rf], bl, accP[rf][ct], 0, 0, 0);
            accP[rf][ct] = __builtin_amdgcn_mfma_f32_16x16x32_bf16(al[rf], bh, accP[rf][ct], 0, 0, 0);
          }
        }
      }
    } else {
      int str = (cidx - 1) >> 2;
      int cc = (cidx - 1) & 3;
#pragma unroll
      for (int l = 0; l < 2; ++l) {
        s16x8 ah[2], al[2];
#pragma unroll
        for (int rf = 0; rf < 2; ++rf) {
          if (rok[rf]) {
            size_t ao = (size_t)grow[rf] * 256 + cc * 64 + l * 32 + klg * 8;
            ah[rf] = *(const s16x8*)&AggH[ao];
            al[rf] = *(const s16x8*)&AggL[ao];
          } else {
            ah[rf] = (s16x8){0, 0, 0, 0, 0, 0, 0, 0};
            al[rf] = (s16x8){0, 0, 0, 0, 0, 0, 0, 0};
          }
        }
        auto do_mfma = [&](f32x4 (&acc)[2][4]) {
#pragma unroll
          for (int ct = 0; ct < 4; ++ct) {
            int fo = ((l * 4 + ct) * 64 + lane) * 8;
            s16x8 bh = *(const s16x8*)&WHc[fo];
            s16x8 bl = *(const s16x8*)&WLc[fo];
#pragma unroll
            for (int rf = 0; rf < 2; ++rf) {
              acc[rf][ct] = __builtin_amdgcn_mfma_f32_16x16x32_bf16(ah[rf], bh, acc[rf][ct], 0, 0, 0);
              acc[rf][ct] = __builtin_amdgcn_mfma_f32_16x16x32_bf16(ah[rf], bl, acc[rf][ct], 0, 0, 0);
              acc[rf][ct] = __builtin_amdgcn_mfma_f32_16x16x32_bf16(al[rf], bh, acc[rf][ct], 0, 0, 0);
            }
          }
        };
        if (str == 0) do_mfma(accP);
        else if (str == 1) do_mfma(accQ);
        else do_mfma(accR);
      }
    }
    __syncthreads();
  }
#pragma unroll
  for (int rf = 0; rf < 2; ++rf)
#pragma unroll
    for (int i = 0; i < 4; ++i) {
      int r = row0 + w * 32 + rf * 16 + klg * 4 + i;
      if (r < n) {
        float av = amp[r], iv = inv[r];
#pragma unroll
        for (int ct = 0; ct < 4; ++ct) {
          int colo = ct * 16 + ar;
          float vv = accP[rf][ct][i] + av * accQ[rf][ct][i] + iv * accR[rf][ct][i] + beff[colo];
          h1[(size_t)r * 64 + colo] = fmaxf(vv, 0.f);
        }
      }
    }
}

// fused conv2: packed gather + 2-col dot (float4 per lane), group reduce
__global__ __launch_bounds__(256) void fused_conv2(
    const float* __restrict__ h1, const float* __restrict__ A,
    const __half* __restrict__ B, const int* __restrict__ rowptr,
    const int* __restrict__ col, const float* __restrict__ amp,
    const float* __restrict__ inv, const float* __restrict__ W2eff,
    const float* __restrict__ b2eff, float* __restrict__ out, int n) {
  int tid = threadIdx.x;
  int lane = tid & 63, wv = tid >> 6;
  int fl = lane & 15, eg = lane >> 4;
  int node = blockIdx.x * 4 + wv;
  if (node >= n) return;
  int s0 = rowptr[node], s1 = rowptr[node + 1];
  float4 sum4, sq4, mn4, mx4;
  gather_stats4(B, col, s0, s1, fl, eg, sum4, sq4, mn4, mx4);
  float4 st0, st1, st2, st3;
  finalize4(A, node, fl, s1 - s0, sum4, sq4, mn4, mx4, st0, st1, st2, st3);
  float av = amp[node], iv = inv[node];
  float4 h4 = *(const float4*)&h1[(size_t)node * 64 + fl * 4];
  const float* W0 = W2eff;
  const float* W1 = W2eff + 832;
  float4 wx0 = *(const float4*)&W0[fl * 4];
  float4 wx1 = *(const float4*)&W1[fl * 4];
  float p0 = wx0.x * h4.x + wx0.y * h4.y + wx0.z * h4.z + wx0.w * h4.w;
  float p1 = wx1.x * h4.x + wx1.y * h4.y + wx1.z * h4.z + wx1.w * h4.w;
#define DOT_STAT(ST, C)                                                       \
  {                                                                           \
    int j = 64 + (C)*64 + fl * 4;                                             \
    float4 a0 = *(const float4*)&W0[j];                                       \
    float4 b0 = *(const float4*)&W0[j + 256];                                 \
    float4 c0 = *(const float4*)&W0[j + 512];                                 \
    float4 a1 = *(const float4*)&W1[j];                                       \
    float4 b1 = *(const float4*)&W1[j + 256];                                 \
    float4 c1 = *(const float4*)&W1[j + 512];                                 \
    p0 += ST.x * fmaf(av, b0.x, fmaf(iv, c0.x, a0.x))                         \
        + ST.y * fmaf(av, b0.y, fmaf(iv, c0.y, a0.y))                         \
        + ST.z * fmaf(av, b0.z, fmaf(iv, c0.z, a0.z))                         \
        + ST.w * fmaf(av, b0.w, fmaf(iv, c0.w, a0.w));                        \
    p1 += ST.x * fmaf(av, b1.x, fmaf(iv, c1.x, a1.x))                         \
        + ST.y * fmaf(av, b1.y, fmaf(iv, c1.y, a1.y))                         \
        + ST.z * fmaf(av, b1.z, fmaf(iv, c1.z, a1.z))                         \
        + ST.w * fmaf(av, b1.w, fmaf(iv, c1.w, a1.w));                        \
  }
  DOT_STAT(st0, 0)
  DOT_STAT(st1, 1)
  DOT_STAT(st2, 2)
  DOT_STAT(st3, 3)
#undef DOT_STAT
#pragma unroll
  for (int m = 1; m <= 8; m <<= 1) {
    p0 += __shfl_xor(p0, m);
    p1 += __shfl_xor(p1, m);
  }
  if (lane == 0) {
    out[(size_t)node * 2 + 0] = p0 + b2eff[0];
    out[(size_t)node * 2 + 1] = p1 + b2eff[1];
  }
}

extern "C" void kernel_launch(void* const* d_in, const int* in_sizes, int n_in,
                              void* d_out, int out_size, void* d_ws, size_t ws_size,
                              hipStream_t stream) {
  const float* x = (const float*)d_in[0];
  const int* ei = (const int*)d_in[1];
  const float* W1_pre = (const float*)d_in[2];
  const float* b1_pre = (const float*)d_in[3];
  const float* W1_post = (const float*)d_in[4];
  const float* b1_post = (const float*)d_in[5];
  const float* W1_lin = (const float*)d_in[6];
  const float* b1_lin = (const float*)d_in[7];
  const float* W2_pre = (const float*)d_in[8];
  const float* b2_pre = (const float*)d_in[9];
  const float* W2_post = (const float*)d_in[10];
  const float* b2_post = (const float*)d_in[11];
  const float* W2_lin = (const float*)d_in[12];
  const float* b2_lin = (const float*)d_in[13];

  const int N = in_sizes[0] / 64;
  const int E = in_sizes[1] / 2;
  const int* srcp = ei;
  const int* dstp = ei + E;
  const int nb = (N + 255) / 256;
  const int nbuk = (N + 1023) >> 10;

  char* ws = (char*)d_ws;
  size_t off = 0;
  auto take = [&](size_t bytes) -> void* {
    void* p = ws + off;
    off = (off + bytes + 255) & ~(size_t)255;
    return p;
  };
  int* deg = (int*)take((size_t)N * 4);
  int* rowptr = (int*)take((size_t)(N + 1) * 4);
  int* cursor = (int*)take((size_t)N * 4);
  int* tmp = (int*)take((size_t)N * 4);
  int* partial = (int*)take(4096);
  int* bcur = (int*)take(4096);
  float* amp = (float*)take((size_t)N * 4);
  float* inv = (float*)take((size_t)N * 4);
  float* avgsum = (float*)take(4);
  unsigned short* W1h = (unsigned short*)take((size_t)64 * 832 * 2);
  unsigned short* W1l = (unsigned short*)take((size_t)64 * 832 * 2);
  float* b1eff = (float*)take(64 * 4);
  float* W2eff = (float*)take((size_t)2 * 832 * 4);
  float* b2eff = (float*)take(2 * 4);
  unsigned short* Wp1h = (unsigned short*)take((size_t)128 * 64 * 2);
  unsigned short* Wp1l = (unsigned short*)take((size_t)128 * 64 * 2);
  unsigned short* Wp2h = (unsigned short*)take((size_t)128 * 64 * 2);
  unsigned short* Wp2l = (unsigned short*)take((size_t)128 * 64 * 2);
  int* col = (int*)take((size_t)E * 4);
  int2* bmaj = (int2*)take((size_t)E * 8);
  float* Abuf = (float*)take((size_t)N * 64 * 4);
  __half* Bbuf = (__half*)take((size_t)N * 64 * 2);
  unsigned short* AggH = (unsigned short*)take((size_t)N * 256 * 2);
  unsigned short* AggL = (unsigned short*)take((size_t)N * 256 * 2);
  float* h1 = (float*)take((size_t)N * 64 * 4);
  (void)ws_size; (void)n_in; (void)out_size;

  hipMemsetAsync(deg, 0, (size_t)N * 4, stream);
  hipMemsetAsync(avgsum, 0, 4, stream);

  make_eff_kernel<<<(ME_S5 + 255) / 256, 256, 0, stream>>>(
      W1_post, b1_post, W1_lin, b1_lin, W2_post, b2_post, W2_lin, b2_lin,
      W1_pre, W2_pre, W1h, W1l, b1eff, W2eff, b2eff, Wp1h, Wp1l, Wp2h, Wp2l);
  hist_kernel<<<(E + 255) / 256, 256, 0, stream>>>(dstp, deg, E);
  avglog_kernel<<<(N + 255) / 256, 256, 0, stream>>>(deg, avgsum, N);
  scan1_kernel<<<nb, 256, 0, stream>>>(deg, tmp, partial, N);
  scan2_kernel<<<1, 1024, 0, stream>>>(partial, nb);
  scan3_kernel<<<nb, 256, 0, stream>>>(deg, tmp, partial, rowptr, cursor, amp, inv,
                                       avgsum, N, E);
  bucket_init<<<1, 128, 0, stream>>>(rowptr, bcur, N, nbuk);
  bucket_scatter<<<(E + ACHUNK - 1) / ACHUNK, 256, 0, stream>>>(srcp, dstp, bcur, bmaj, E, nbuk);
  bucket_fill<<<nbuk, 1024, 0, stream>>>(bmaj, rowptr, cursor, col, N, E);

  // conv1
  pre_mfma<<<(N + 127) / 128, 256, 0, stream>>>(x, Wp1h, Wp1l, b1_pre, Abuf, Bbuf, N);
  aggr_pack<<<(N + 3) / 4, 256, 0, stream>>>(Abuf, Bbuf, rowptr, col, AggH, AggL, N);
  post1_kernel<<<(N + 127) / 128, 256, 0, stream>>>(x, AggH, AggL, amp, inv,
                                                    W1h, W1l, b1eff, h1, N);
  // conv2
  pre_mfma<<<(N + 127) / 128, 256, 0, stream>>>(h1, Wp2h, Wp2l, b2_pre, Abuf, Bbuf, N);
  fused_conv2<<<(N + 3) / 4, 256, 0, stream>>>(h1, Abuf, Bbuf, rowptr, col, amp, inv,
                                               W2eff, b2eff, (float*)d_out, N);
}

// Round 13
// 395.624 us; speedup vs baseline: 1.3514x; 1.3514x over previous
//
#include <hip/hip_runtime.h>
#include <hip/hip_fp16.h>
#include <math.h>

// ---------------------------------------------------------------------------
// PNA (2 conv layers) on MI355X.
//   pre:  [A|B] = x @ [Wl|Wr]^T (+b on B)   (bf16-split MFMA GEMM; B -> fp16)
//   CSR build: hist -> scan -> 2-level bucket sort (no write amplification)
//   gathers (R10 form): 1 node/wave, lane=feat, fp16 B, 16-deep pipeline
//   aggr: stored as SINGLE fp16 (halves Agg traffic)
//   post1: single-product fp16 MFMA GEMM, fragment-major fp16 weights,
//          LDS double-buffered weight staging via global_load_lds
//   fused_conv2: gather + 2-col dot (no aggr materialization)
// ---------------------------------------------------------------------------

typedef __attribute__((ext_vector_type(4))) float f32x4;
typedef __attribute__((ext_vector_type(8))) short s16x8;
typedef __attribute__((ext_vector_type(8))) _Float16 f16x8;

#define AS1 __attribute__((address_space(1)))
#define AS3 __attribute__((address_space(3)))
__device__ inline void gload16(const void* g, void* l) {
  __builtin_amdgcn_global_load_lds((AS1 const void*)g, (AS3 void*)l, 16, 0, 0);
}

__device__ inline unsigned short f2bf(float f) {
  unsigned int u = __float_as_uint(f);
  unsigned int r = u + 0x7fff + ((u >> 16) & 1);  // RNE
  return (unsigned short)(r >> 16);
}
__device__ inline float bf2f(unsigned short s) {
  return __uint_as_float(((unsigned int)s) << 16);
}
// truncation split: v = hi + rest, lo = bf16(rest)
__device__ inline void tsplit(float v, unsigned short& h, unsigned short& l) {
  unsigned int u = __float_as_uint(v);
  unsigned int hu = u & 0xffff0000u;
  h = (unsigned short)(hu >> 16);
  float lf = v - __uint_as_float(hu);
  l = (unsigned short)(__float_as_uint(lf) >> 16);
}

#define ME_S0 (64 * 832)
#define ME_S1 (ME_S0 + 64)
#define ME_S2 (ME_S1 + 2 * 832)
#define ME_S3 (ME_S2 + 2)
#define ME_S4 (ME_S3 + 128 * 64)
#define ME_S5 (ME_S4 + 128 * 64)

__global__ void make_eff_kernel(const float* __restrict__ W1_post, const float* __restrict__ b1_post,
                                const float* __restrict__ W1_lin, const float* __restrict__ b1_lin,
                                const float* __restrict__ W2_post, const float* __restrict__ b2_post,
                                const float* __restrict__ W2_lin, const float* __restrict__ b2_lin,
                                const float* __restrict__ W1_pre, const float* __restrict__ W2_pre,
                                __half* __restrict__ W1f,
                                float* __restrict__ b1eff,
                                float* __restrict__ W2eff, float* __restrict__ b2eff,
                                unsigned short* __restrict__ Wp1h, unsigned short* __restrict__ Wp1l,
                                unsigned short* __restrict__ Wp2h, unsigned short* __restrict__ Wp2l) {
  int id = blockIdx.x * blockDim.x + threadIdx.x;
  if (id < ME_S0) {
    int o = id / 832, k = id - o * 832;
    float s = 0.f;
#pragma unroll 8
    for (int j = 0; j < 64; ++j) s = fmaf(W1_lin[o * 64 + j], W1_post[j * 832 + k], s);
    // fragment-major layout: lane = klg*16 + ar holds elems j for (col, k)
    int q = k >> 5, klg = (k >> 3) & 3, jj = k & 7;
    int ct = o >> 4, ar = o & 15;
    int idx = ((q * 4 + ct) * 64 + (klg * 16 + ar)) * 8 + jj;
    W1f[idx] = __float2half(s);
  } else if (id < ME_S1) {
    int o = id - ME_S0;
    float s = b1_lin[o];
    for (int j = 0; j < 64; ++j) s = fmaf(W1_lin[o * 64 + j], b1_post[j], s);
    b1eff[o] = s;
  } else if (id < ME_S2) {
    int t = id - ME_S1;
    int o = t / 832, k = t - o * 832;
    W2eff[t] = fmaf(W2_lin[o * 2 + 0], W2_post[k], W2_lin[o * 2 + 1] * W2_post[832 + k]);
  } else if (id < ME_S3) {
    int o = id - ME_S2;
    b2eff[o] = b2_lin[o] + W2_lin[o * 2 + 0] * b2_post[0] + W2_lin[o * 2 + 1] * b2_post[1];
  } else if (id < ME_S4) {
    int t = id - ME_S3;
    int c = t >> 6, k = t & 63;
    float v = (c < 64) ? W1_pre[c * 128 + k] : W1_pre[(c - 64) * 128 + 64 + k];
    unsigned short h = f2bf(v);
    Wp1h[t] = h;
    Wp1l[t] = f2bf(v - bf2f(h));
  } else if (id < ME_S5) {
    int t = id - ME_S4;
    int c = t >> 6, k = t & 63;
    float v = (c < 64) ? W2_pre[c * 128 + k] : W2_pre[(c - 64) * 128 + 64 + k];
    unsigned short h = f2bf(v);
    Wp2h[t] = h;
    Wp2l[t] = f2bf(v - bf2f(h));
  }
}

__global__ void hist_kernel(const int* __restrict__ dst, int* __restrict__ deg, int E) {
  int i = blockIdx.x * blockDim.x + threadIdx.x;
  if (i < E) atomicAdd(&deg[dst[i]], 1);
}

__global__ void avglog_kernel(const int* __restrict__ deg, float* __restrict__ out_sum, int n) {
  int i = blockIdx.x * blockDim.x + threadIdx.x;
  float v = (i < n) ? logf((float)deg[i] + 1.0f) : 0.0f;
  __shared__ float red[4];
  int lane = threadIdx.x & 63, wid = threadIdx.x >> 6;
  for (int off = 32; off; off >>= 1) v += __shfl_down(v, off);
  if (lane == 0) red[wid] = v;
  __syncthreads();
  if (threadIdx.x == 0) atomicAdd(out_sum, red[0] + red[1] + red[2] + red[3]);
}

__global__ void scan1_kernel(const int* __restrict__ deg, int* __restrict__ excl,
                             int* __restrict__ partial, int n) {
  __shared__ int wsums[4];
  int tid = threadIdx.x, b = blockIdx.x;
  int i = b * 256 + tid;
  int lane = tid & 63, wid = tid >> 6;
  int v = (i < n) ? deg[i] : 0;
  int x = v;
  for (int off = 1; off < 64; off <<= 1) {
    int t = __shfl_up(x, off);
    if (lane >= off) x += t;
  }
  if (lane == 63) wsums[wid] = x;
  __syncthreads();
  int wo = 0;
#pragma unroll
  for (int j = 0; j < 4; ++j) wo += (j < wid) ? wsums[j] : 0;
  if (i < n) excl[i] = wo + x - v;
  if (tid == 255) partial[b] = wo + x;
}

__global__ void scan2_kernel(int* __restrict__ partial, int nb) {
  __shared__ int wsums[16];
  int tid = threadIdx.x;
  int lane = tid & 63, wid = tid >> 6;
  int v = (tid < nb) ? partial[tid] : 0;
  int x = v;
  for (int off = 1; off < 64; off <<= 1) {
    int t = __shfl_up(x, off);
    if (lane >= off) x += t;
  }
  if (lane == 63) wsums[wid] = x;
  __syncthreads();
  if (wid == 0) {
    int w2 = (lane < 16) ? wsums[lane] : 0;
    for (int off = 1; off < 16; off <<= 1) {
      int t = __shfl_up(w2, off);
      if (lane >= off) w2 += t;
    }
    if (lane < 16) wsums[lane] = w2;
  }
  __syncthreads();
  int wo = (wid > 0) ? wsums[wid - 1] : 0;
  if (tid < nb) partial[tid] = wo + x - v;
}

__global__ void scan3_kernel(const int* __restrict__ deg, const int* __restrict__ excl,
                             const int* __restrict__ partial, int* __restrict__ rowptr,
                             int* __restrict__ cursor, float* __restrict__ amp,
                             float* __restrict__ inv, const float* __restrict__ avgsum,
                             int n, int E) {
  int i = blockIdx.x * 256 + threadIdx.x;
  if (i < n) {
    int r = excl[i] + partial[blockIdx.x];
    rowptr[i] = r;
    cursor[i] = r;
    int v = deg[i];
    float dnm = (float)(v > 0 ? v : 1);
    float a = logf(dnm + 1.0f) * ((float)n / avgsum[0]);
    amp[i] = a;
    inv[i] = 1.0f / a;
  }
  if (i == 0) rowptr[n] = E;
}

// ---- 2-level bucket sort CSR build (bucket = 1024 dst nodes) ----
#define BMAX 104
#define BINCAP 72
#define ACHUNK 4096

__global__ void bucket_init(const int* __restrict__ rowptr, int* __restrict__ bcur,
                            int n, int nbuk) {
  int b = blockIdx.x * blockDim.x + threadIdx.x;
  if (b < nbuk) {
    int idx = b << 10;
    if (idx > n) idx = n;
    bcur[b] = rowptr[idx];
  }
}

__global__ __launch_bounds__(256) void bucket_scatter(
    const int* __restrict__ src, const int* __restrict__ dst,
    int* __restrict__ bcur, int2* __restrict__ bmaj, int E, int nbuk) {
  __shared__ int bin_cnt[BMAX];
  __shared__ int bin_len[BMAX];
  __shared__ int bin_base[BMAX];
  __shared__ int bin_pref[BMAX + 1];
  __shared__ int2 bin_buf[BMAX * BINCAP];
  int tid = threadIdx.x;
  for (int b = tid; b < BMAX; b += 256) bin_cnt[b] = 0;
  __syncthreads();
  int start = blockIdx.x * ACHUNK;
  int end = start + ACHUNK;
  if (end > E) end = E;
  for (int i = start + tid; i < end; i += 256) {
    int s = src[i], d = dst[i];
    int b = d >> 10;
    int slot = atomicAdd(&bin_cnt[b], 1);
    if (slot < BINCAP) {
      bin_buf[b * BINCAP + slot] = make_int2(s, d);
    } else {
      int pos = atomicAdd(&bcur[b], 1);
      bmaj[pos] = make_int2(s, d);
    }
  }
  __syncthreads();
  if (tid < nbuk) {
    int c = bin_cnt[tid];
    bin_len[tid] = (c < BINCAP) ? c : BINCAP;
  }
  __syncthreads();
  if (tid == 0) {
    int acc = 0;
    for (int b = 0; b < nbuk; ++b) {
      bin_pref[b] = acc;
      acc += bin_len[b];
    }
    bin_pref[nbuk] = acc;
  }
  __syncthreads();
  if (tid < nbuk && bin_len[tid] > 0) bin_base[tid] = atomicAdd(&bcur[tid], bin_len[tid]);
  __syncthreads();
  int T = bin_pref[nbuk];
  for (int t = tid; t < T; t += 256) {
    int lo = 0, hi = nbuk - 1;
    while (lo < hi) {
      int mid = (lo + hi + 1) >> 1;
      if (bin_pref[mid] <= t) lo = mid; else hi = mid - 1;
    }
    int j = t - bin_pref[lo];
    bmaj[bin_base[lo] + j] = bin_buf[lo * BINCAP + j];
  }
}

__global__ __launch_bounds__(1024) void bucket_fill(
    const int2* __restrict__ bmaj, const int* __restrict__ rowptr,
    int* __restrict__ cursor, int* __restrict__ col, int n, int E) {
  int b = blockIdx.x;
  int i0 = b << 10;
  int i1 = i0 + 1024;
  if (i0 > n) i0 = n;
  if (i1 > n) i1 = n;
  int start = rowptr[i0];
  int end = rowptr[i1];
  for (int e = start + (int)threadIdx.x; e < end; e += 1024) {
    int2 p = bmaj[e];
    int pos = atomicAdd(&cursor[p.y], 1);
    col[pos] = p.x;
  }
}

// [A|B] = x @ [Wl|Wr]^T, bias folded into B (B stored fp16). 128-row blocks.
__global__ __launch_bounds__(256, 2) void pre_mfma(
    const float* __restrict__ xin, const unsigned short* __restrict__ Wh,
    const unsigned short* __restrict__ Wl, const float* __restrict__ bias,
    float* __restrict__ A, __half* __restrict__ Bo, int n) {
  __shared__ __attribute__((aligned(16))) unsigned short XH[128 * 64];
  __shared__ __attribute__((aligned(16))) unsigned short XL[128 * 64];
  int tid = threadIdx.x;
  int lane = tid & 63, w = tid >> 6;
  int row0 = blockIdx.x * 128;
  int sr = tid >> 1, hf = tid & 1;
  int grow = row0 + sr;
  {
    float v[32];
    if (grow < n) {
      const float4* p = (const float4*)(xin + (size_t)grow * 64 + hf * 32);
#pragma unroll
      for (int q = 0; q < 8; ++q) {
        float4 t = p[q];
        v[q * 4 + 0] = t.x; v[q * 4 + 1] = t.y; v[q * 4 + 2] = t.z; v[q * 4 + 3] = t.w;
      }
    } else {
#pragma unroll
      for (int j = 0; j < 32; ++j) v[j] = 0.f;
    }
    unsigned short hs[32], ls[32];
#pragma unroll
    for (int j = 0; j < 32; ++j) tsplit(v[j], hs[j], ls[j]);
    int rsw = sr & 7;
#pragma unroll
    for (int q = 0; q < 4; ++q) {
      int g = hf * 4 + q;
      int off = sr * 64 + ((g ^ rsw) << 3);
      *(s16x8*)&XH[off] = *(const s16x8*)&hs[q * 8];
      *(s16x8*)&XL[off] = *(const s16x8*)&ls[q * 8];
    }
  }
  __syncthreads();
  int ar = lane & 15, klg = lane >> 4;
  f32x4 acc[2][8];
#pragma unroll
  for (int rf = 0; rf < 2; ++rf)
#pragma unroll
    for (int ct = 0; ct < 8; ++ct) acc[rf][ct] = (f32x4){0.f, 0.f, 0.f, 0.f};
#pragma unroll
  for (int kk = 0; kk < 64; kk += 32) {
    s16x8 ah[2], al[2];
#pragma unroll
    for (int rf = 0; rf < 2; ++rf) {
      int lrow = w * 32 + rf * 16 + ar;
      int g = (kk >> 3) + klg;
      int off = lrow * 64 + ((g ^ (lrow & 7)) << 3);
      ah[rf] = *(const s16x8*)&XH[off];
      al[rf] = *(const s16x8*)&XL[off];
    }
    int ko = kk + klg * 8;
#pragma unroll
    for (int ct = 0; ct < 8; ++ct) {
      size_t br = (size_t)(ct * 16 + ar) * 64 + ko;
      s16x8 bh = *(const s16x8*)&Wh[br];
      s16x8 bl = *(const s16x8*)&Wl[br];
#pragma unroll
      for (int rf = 0; rf < 2; ++rf) {
        acc[rf][ct] = __builtin_amdgcn_mfma_f32_16x16x32_bf16(ah[rf], bh, acc[rf][ct], 0, 0, 0);
        acc[rf][ct] = __builtin_amdgcn_mfma_f32_16x16x32_bf16(ah[rf], bl, acc[rf][ct], 0, 0, 0);
        acc[rf][ct] = __builtin_amdgcn_mfma_f32_16x16x32_bf16(al[rf], bh, acc[rf][ct], 0, 0, 0);
      }
    }
  }
#pragma unroll
  for (int rf = 0; rf < 2; ++rf)
#pragma unroll
    for (int i = 0; i < 4; ++i) {
      int r = row0 + w * 32 + rf * 16 + klg * 4 + i;
      if (r < n) {
#pragma unroll
        for (int ct = 0; ct < 8; ++ct) {
          int c = ct * 16 + ar;
          float vv = acc[rf][ct][i];
          if (ct < 4) A[(size_t)r * 64 + c] = vv;
          else Bo[(size_t)r * 64 + (c - 64)] = __float2half(vv + bias[c - 64]);
        }
      }
    }
}

// ---- shared gather macro body: 1 node/wave, lane=feat, fp16 B, 16-deep ----
#define GATHER_STATS                                                        \
  float sum = 0.f, sq = 0.f, mx = -3.4e38f, mn = 3.4e38f;                   \
  int e = s0;                                                               \
  for (; e + 16 <= s1; e += 16) {                                           \
    int idx[16];                                                            \
    _Pragma("unroll") for (int j = 0; j < 16; ++j) idx[j] = col[e + j];     \
    __half hv[16];                                                          \
    _Pragma("unroll") for (int j = 0; j < 16; ++j)                          \
        hv[j] = B[(size_t)idx[j] * 64 + lane];                              \
    _Pragma("unroll") for (int j = 0; j < 16; ++j) {                        \
      float b = __half2float(hv[j]);                                        \
      sum += b; sq = fmaf(b, b, sq);                                        \
      mx = fmaxf(mx, b); mn = fminf(mn, b);                                 \
    }                                                                       \
  }                                                                         \
  for (; e + 4 <= s1; e += 4) {                                             \
    int idx[4];                                                             \
    _Pragma("unroll") for (int j = 0; j < 4; ++j) idx[j] = col[e + j];      \
    __half hv[4];                                                           \
    _Pragma("unroll") for (int j = 0; j < 4; ++j)                           \
        hv[j] = B[(size_t)idx[j] * 64 + lane];                              \
    _Pragma("unroll") for (int j = 0; j < 4; ++j) {                         \
      float b = __half2float(hv[j]);                                        \
      sum += b; sq = fmaf(b, b, sq);                                        \
      mx = fmaxf(mx, b); mn = fminf(mn, b);                                 \
    }                                                                       \
  }                                                                         \
  for (; e < s1; ++e) {                                                     \
    float b = __half2float(B[(size_t)col[e] * 64 + lane]);                  \
    sum += b; sq = fmaf(b, b, sq);                                          \
    mx = fmaxf(mx, b); mn = fminf(mn, b);                                   \
  }

// wave per node: CSR gather stats of fp16 B -> fp16 Agg (single precision)
__global__ __launch_bounds__(256) void aggr_pack(
    const float* __restrict__ A, const __half* __restrict__ B,
    const int* __restrict__ rowptr, const int* __restrict__ col,
    __half* __restrict__ AggF, int n) {
  int tid = threadIdx.x;
  int lane = tid & 63, wv = tid >> 6;
  int node = blockIdx.x * 4 + wv;
  if (node >= n) return;
  int s0 = rowptr[node], s1 = rowptr[node + 1];
  GATHER_STATS
  int d = s1 - s0;
  float st[4];
  if (d > 0) {
    float idn = 1.0f / (float)d;
    float mB = sum * idn;
    float a = A[(size_t)node * 64 + lane];
    st[0] = a + mB;
    st[1] = a + mn;
    st[2] = a + mx;
    float var = fmaf(-mB, mB, sq * idn);
    st[3] = sqrtf(fmaxf(var, 0.0f) + 1e-5f);
  } else {
    st[0] = 0.f; st[1] = 0.f; st[2] = 0.f; st[3] = sqrtf(1e-5f);
  }
  size_t o = (size_t)node * 256 + lane;
#pragma unroll
  for (int c = 0; c < 4; ++c) AggF[o + c * 64] = __float2half(st[c]);
}

// post1: single-product fp16 MFMA GEMM. 128-row blocks, 4 waves x 32 rows.
// Weights fp16 fragment-major, streamed through LDS in 13 double-buffered 8KB
// chunks via global_load_lds. chunk cidx = q{2cidx,2cidx+1}; cidx 0 = x-stream;
// cidx>=1 -> stream str=(cidx-1)>>2 (P/Q/R), agg chunk cc=(cidx-1)&3.
__global__ __launch_bounds__(256) void post1_kernel(
    const float* __restrict__ x, const __half* __restrict__ AggF,
    const float* __restrict__ amp, const float* __restrict__ inv,
    const __half* __restrict__ Wf, const float* __restrict__ beff,
    float* __restrict__ h1, int n) {
  __shared__ __attribute__((aligned(16))) __half WS[8192];  // 2 x 4096 halfs
  int tid = threadIdx.x;
  int lane = tid & 63, w = tid >> 6;
  int row0 = blockIdx.x * 128;
  int ar = lane & 15, klg = lane >> 4;
  int grow[2];
  bool rok[2];
#pragma unroll
  for (int rf = 0; rf < 2; ++rf) {
    grow[rf] = row0 + w * 32 + rf * 16 + ar;
    rok[rf] = grow[rf] < n;
  }
  f32x4 accP[2][4], accQ[2][4], accR[2][4];
#pragma unroll
  for (int rf = 0; rf < 2; ++rf)
#pragma unroll
    for (int ct = 0; ct < 4; ++ct) {
      accP[rf][ct] = (f32x4){0.f, 0.f, 0.f, 0.f};
      accQ[rf][ct] = (f32x4){0.f, 0.f, 0.f, 0.f};
      accR[rf][ct] = (f32x4){0.f, 0.f, 0.f, 0.f};
    }

  // async-stage chunk c (4096 halfs) into buffer buf; 4 waves x 2 x 1KB loads
  auto stage = [&](int c, int buf) {
    const __half* srcbase = Wf + c * 4096;
    __half* dstbase = &WS[buf * 4096];
#pragma unroll
    for (int i = 0; i < 2; ++i) {
      int boff = w * 1024 + i * 512 + lane * 8;
      gload16(srcbase + boff, dstbase + boff);
    }
  };

  stage(0, 0);
  __syncthreads();  // drains vmcnt -> chunk 0 ready

#pragma unroll
  for (int cidx = 0; cidx < 13; ++cidx) {
    int cur = cidx & 1;
    if (cidx + 1 < 13) stage(cidx + 1, cur ^ 1);
    const __half* Wc = &WS[cur * 4096];
    if (cidx == 0) {
      // x stream (q = 0,1) -> accP
#pragma unroll
      for (int l = 0; l < 2; ++l) {
        f16x8 ah[2];
#pragma unroll
        for (int rf = 0; rf < 2; ++rf) {
          _Float16 hs[8];
          if (rok[rf]) {
            const float* p = x + (size_t)grow[rf] * 64 + l * 32 + klg * 8;
            float4 v0 = *(const float4*)p;
            float4 v1 = *(const float4*)(p + 4);
            hs[0] = (_Float16)v0.x; hs[1] = (_Float16)v0.y;
            hs[2] = (_Float16)v0.z; hs[3] = (_Float16)v0.w;
            hs[4] = (_Float16)v1.x; hs[5] = (_Float16)v1.y;
            hs[6] = (_Float16)v1.z; hs[7] = (_Float16)v1.w;
          } else {
#pragma unroll
            for (int j = 0; j < 8; ++j) hs[j] = (_Float16)0.f;
          }
          ah[rf] = *(const f16x8*)hs;
        }
#pragma unroll
        for (int ct = 0; ct < 4; ++ct) {
          int fo = ((l * 4 + ct) * 64 + lane) * 8;
          f16x8 bw = *(const f16x8*)&Wc[fo];
#pragma unroll
          for (int rf = 0; rf < 2; ++rf)
            accP[rf][ct] = __builtin_amdgcn_mfma_f32_16x16x32_f16(ah[rf], bw, accP[rf][ct], 0, 0, 0);
        }
      }
    } else {
      int str = (cidx - 1) >> 2;  // compile-time after unroll
      int cc = (cidx - 1) & 3;
#pragma unroll
      for (int l = 0; l < 2; ++l) {
        f16x8 ah[2];
#pragma unroll
        for (int rf = 0; rf < 2; ++rf) {
          if (rok[rf]) {
            size_t ao = (size_t)grow[rf] * 256 + cc * 64 + l * 32 + klg * 8;
            ah[rf] = *(const f16x8*)&AggF[ao];
          } else {
            _Float16 z[8] = {};
            ah[rf] = *(const f16x8*)z;
          }
        }
        auto do_mfma = [&](f32x4 (&acc)[2][4]) {
#pragma unroll
          for (int ct = 0; ct < 4; ++ct) {
            int fo = ((l * 4 + ct) * 64 + lane) * 8;
            f16x8 bw = *(const f16x8*)&Wc[fo];
#pragma unroll
            for (int rf = 0; rf < 2; ++rf)
              acc[rf][ct] = __builtin_amdgcn_mfma_f32_16x16x32_f16(ah[rf], bw, acc[rf][ct], 0, 0, 0);
          }
        };
        if (str == 0) do_mfma(accP);
        else if (str == 1) do_mfma(accQ);
        else do_mfma(accR);
      }
    }
    __syncthreads();  // drains staged loads; next buffer ready
  }
  // epilogue
#pragma unroll
  for (int rf = 0; rf < 2; ++rf)
#pragma unroll
    for (int i = 0; i < 4; ++i) {
      int r = row0 + w * 32 + rf * 16 + klg * 4 + i;
      if (r < n) {
        float av = amp[r], iv = inv[r];
#pragma unroll
        for (int ct = 0; ct < 4; ++ct) {
          int colo = ct * 16 + ar;
          float vv = accP[rf][ct][i] + av * accQ[rf][ct][i] + iv * accR[rf][ct][i] + beff[colo];
          h1[(size_t)r * 64 + colo] = fmaxf(vv, 0.f);
        }
      }
    }
}

// fused conv2: wave/node stats (16-deep fp16 gather) + 2-col dot, wave reduce
__global__ __launch_bounds__(256) void fused_conv2(
    const float* __restrict__ h1, const float* __restrict__ A,
    const __half* __restrict__ B, const int* __restrict__ rowptr,
    const int* __restrict__ col, const float* __restrict__ amp,
    const float* __restrict__ inv, const float* __restrict__ W2eff,
    const float* __restrict__ b2eff, float* __restrict__ out, int n) {
  int tid = threadIdx.x;
  int lane = tid & 63, wv = tid >> 6;
  int node = blockIdx.x * 4 + wv;
  if (node >= n) return;
  int s0 = rowptr[node], s1 = rowptr[node + 1];
  GATHER_STATS
  int d = s1 - s0;
  float st[4];
  if (d > 0) {
    float idn = 1.0f / (float)d;
    float mB = sum * idn;
    float a = A[(size_t)node * 64 + lane];
    st[0] = a + mB;
    st[1] = a + mn;
    st[2] = a + mx;
    float var = fmaf(-mB, mB, sq * idn);
    st[3] = sqrtf(fmaxf(var, 0.0f) + 1e-5f);
  } else {
    st[0] = 0.f; st[1] = 0.f; st[2] = 0.f; st[3] = sqrtf(1e-5f);
  }
  float av = amp[node], iv = inv[node];
  float xv = h1[(size_t)node * 64 + lane];
  float p0 = W2eff[lane] * xv;
  float p1 = W2eff[832 + lane] * xv;
#pragma unroll
  for (int m = 0; m < 4; ++m) {
    int j = m * 64 + lane;
    p0 = fmaf(st[m], fmaf(av, W2eff[320 + j], fmaf(iv, W2eff[576 + j], W2eff[64 + j])), p0);
    p1 = fmaf(st[m], fmaf(av, W2eff[832 + 320 + j], fmaf(iv, W2eff[832 + 576 + j], W2eff[832 + 64 + j])), p1);
  }
#pragma unroll
  for (int m = 32; m; m >>= 1) {
    p0 += __shfl_xor(p0, m);
    p1 += __shfl_xor(p1, m);
  }
  if (lane == 0) {
    out[(size_t)node * 2 + 0] = p0 + b2eff[0];
    out[(size_t)node * 2 + 1] = p1 + b2eff[1];
  }
}

extern "C" void kernel_launch(void* const* d_in, const int* in_sizes, int n_in,
                              void* d_out, int out_size, void* d_ws, size_t ws_size,
                              hipStream_t stream) {
  const float* x = (const float*)d_in[0];
  const int* ei = (const int*)d_in[1];
  const float* W1_pre = (const float*)d_in[2];
  const float* b1_pre = (const float*)d_in[3];
  const float* W1_post = (const float*)d_in[4];
  const float* b1_post = (const float*)d_in[5];
  const float* W1_lin = (const float*)d_in[6];
  const float* b1_lin = (const float*)d_in[7];
  const float* W2_pre = (const float*)d_in[8];
  const float* b2_pre = (const float*)d_in[9];
  const float* W2_post = (const float*)d_in[10];
  const float* b2_post = (const float*)d_in[11];
  const float* W2_lin = (const float*)d_in[12];
  const float* b2_lin = (const float*)d_in[13];

  const int N = in_sizes[0] / 64;
  const int E = in_sizes[1] / 2;
  const int* srcp = ei;
  const int* dstp = ei + E;
  const int nb = (N + 255) / 256;
  const int nbuk = (N + 1023) >> 10;

  char* ws = (char*)d_ws;
  size_t off = 0;
  auto take = [&](size_t bytes) -> void* {
    void* p = ws + off;
    off = (off + bytes + 255) & ~(size_t)255;
    return p;
  };
  int* deg = (int*)take((size_t)N * 4);
  int* rowptr = (int*)take((size_t)(N + 1) * 4);
  int* cursor = (int*)take((size_t)N * 4);
  int* tmp = (int*)take((size_t)N * 4);
  int* partial = (int*)take(4096);
  int* bcur = (int*)take(4096);
  float* amp = (float*)take((size_t)N * 4);
  float* inv = (float*)take((size_t)N * 4);
  float* avgsum = (float*)take(4);
  __half* W1f = (__half*)take((size_t)64 * 832 * 2);
  float* b1eff = (float*)take(64 * 4);
  float* W2eff = (float*)take((size_t)2 * 832 * 4);
  float* b2eff = (float*)take(2 * 4);
  unsigned short* Wp1h = (unsigned short*)take((size_t)128 * 64 * 2);
  unsigned short* Wp1l = (unsigned short*)take((size_t)128 * 64 * 2);
  unsigned short* Wp2h = (unsigned short*)take((size_t)128 * 64 * 2);
  unsigned short* Wp2l = (unsigned short*)take((size_t)128 * 64 * 2);
  int* col = (int*)take((size_t)E * 4);
  int2* bmaj = (int2*)take((size_t)E * 8);
  float* Abuf = (float*)take((size_t)N * 64 * 4);
  __half* Bbuf = (__half*)take((size_t)N * 64 * 2);
  __half* AggF = (__half*)take((size_t)N * 256 * 2);
  float* h1 = (float*)take((size_t)N * 64 * 4);
  (void)ws_size; (void)n_in; (void)out_size;

  hipMemsetAsync(deg, 0, (size_t)N * 4, stream);
  hipMemsetAsync(avgsum, 0, 4, stream);

  make_eff_kernel<<<(ME_S5 + 255) / 256, 256, 0, stream>>>(
      W1_post, b1_post, W1_lin, b1_lin, W2_post, b2_post, W2_lin, b2_lin,
      W1_pre, W2_pre, W1f, b1eff, W2eff, b2eff, Wp1h, Wp1l, Wp2h, Wp2l);
  hist_kernel<<<(E + 255) / 256, 256, 0, stream>>>(dstp, deg, E);
  avglog_kernel<<<(N + 255) / 256, 256, 0, stream>>>(deg, avgsum, N);
  scan1_kernel<<<nb, 256, 0, stream>>>(deg, tmp, partial, N);
  scan2_kernel<<<1, 1024, 0, stream>>>(partial, nb);
  scan3_kernel<<<nb, 256, 0, stream>>>(deg, tmp, partial, rowptr, cursor, amp, inv,
                                       avgsum, N, E);
  bucket_init<<<1, 128, 0, stream>>>(rowptr, bcur, N, nbuk);
  bucket_scatter<<<(E + ACHUNK - 1) / ACHUNK, 256, 0, stream>>>(srcp, dstp, bcur, bmaj, E, nbuk);
  bucket_fill<<<nbuk, 1024, 0, stream>>>(bmaj, rowptr, cursor, col, N, E);

  // conv1
  pre_mfma<<<(N + 127) / 128, 256, 0, stream>>>(x, Wp1h, Wp1l, b1_pre, Abuf, Bbuf, N);
  aggr_pack<<<(N + 3) / 4, 256, 0, stream>>>(Abuf, Bbuf, rowptr, col, AggF, N);
  post1_kernel<<<(N + 127) / 128, 256, 0, stream>>>(x, AggF, amp, inv, W1f, b1eff, h1, N);
  // conv2
  pre_mfma<<<(N + 127) / 128, 256, 0, stream>>>(h1, Wp2h, Wp2l, b2_pre, Abuf, Bbuf, N);
  fused_conv2<<<(N + 3) / 4, 256, 0, stream>>>(h1, Abuf, Bbuf, rowptr, col, amp, inv,
                                               W2eff, b2eff, (float*)d_out, N);
}